// Round 7
// baseline (99.296 us; speedup 1.0000x reference)
//
#include <hip/hip_runtime.h>

// GPLoss: gradient-profile loss, scalar output. Single-read unified main pass.
// Block = 256 thr, one RB-row band of one plane; thread owns cols {2t, 2t+1}.
// Dual independent row-streams per thread (rows k and k+RB/2) for 2x MLP/ILP.
// Row stats reduced in-wave via DPP (VALU pipe); col stats per-thread ->
// atomic-free colPart slots.
// ws: colPart f32[96*NB][6][512] ; rowPart f32[96*NB][2] ; dblk f64[192]

#define DPP_ADD(x, ctrl, rmask) \
  x += __int_as_float(__builtin_amdgcn_update_dpp(0, __float_as_int(x), ctrl, rmask, 0xf, false))

__device__ __forceinline__ float wave_dpp_sum(float x){
  DPP_ADD(x, 0x111, 0xf);   // row_shr:1
  DPP_ADD(x, 0x112, 0xf);   // row_shr:2
  DPP_ADD(x, 0x114, 0xf);   // row_shr:4
  DPP_ADD(x, 0x118, 0xf);   // row_shr:8
  DPP_ADD(x, 0x142, 0xa);   // row_bcast:15 -> rows 1,3
  DPP_ADD(x, 0x143, 0xc);   // row_bcast:31 -> rows 2,3
  return x;                 // lane 63 holds the 64-lane sum
}

__device__ __forceinline__ float cos_sim(float dot, float sx, float sr){
  float nx = fmaxf(sqrtf(sx), 1e-12f);
  float nr = fmaxf(sqrtf(sr), 1e-12f);
  return dot / (nx * nr);
}

template<int RB>   // rows per band; NB = 512/RB blocks per plane
__global__ __launch_bounds__(256) void gp_uni(
    const float* __restrict__ X, const float* __restrict__ R,
    float* __restrict__ rowPart, float* __restrict__ colPart)
{
  constexpr int NB = 512 / RB;
  constexpr int HS = RB / 2;          // rows per stream
  const int bid = blockIdx.x;
  const int p = bid / NB, b = bid % NB;
  const int tid = threadIdx.x, w = tid >> 6, l = tid & 63;
  const size_t plane = (size_t)p * (512u*512u);
  const float* xp = X + plane;
  const float* rp = R + plane;
  const int c  = 2*tid;
  const int cn = (c+2 < 512) ? c+2 : 511;   // f_v neighbor col (clamped)
  const bool tlast = (tid == 255);           // col 511: no f_v diff
  const int h0 = b * RB;

  __shared__ float rowbuf[RB][4][6];

  float v00=0.f,v01=0.f,v02=0.f, v10=0.f,v11=0.f,v12=0.f;
  float h00=0.f,h01=0.f,h02=0.f, h10=0.f,h11=0.f,h12=0.f;

  // stream A: rows [h0, h0+HS) ; stream B: rows [h0+HS, h0+RB)
  const float* xrA = xp + (size_t)h0*512;
  const float* rrA = rp + (size_t)h0*512;
  const float* xrB = xp + (size_t)(h0+HS)*512;
  const float* rrB = rp + (size_t)(h0+HS)*512;
  float2 xcA = *(const float2*)(xrA + c), rcA = *(const float2*)(rrA + c);
  float2 xcB = *(const float2*)(xrB + c), rcB = *(const float2*)(rrB + c);
  float  xnA = xrA[cn], rnA = rrA[cn];
  float  xnB = xrB[cn], rnB = rrB[cn];

  for (int k = 0; k < HS; ++k){
    const int hA  = h0 + k;                     // hA <= 510 always
    const int hB  = h0 + HS + k;
    const int hnB = (hB + 1 < 512) ? hB + 1 : 511;  // h==511: next==cur -> 0
    const float* xA = xp + (size_t)(hA+1)*512;
    const float* rA = rp + (size_t)(hA+1)*512;
    const float* xB = xp + (size_t)hnB*512;
    const float* rB = rp + (size_t)hnB*512;
    const float2 nxA = *(const float2*)(xA + c), nrA = *(const float2*)(rA + c);
    const float2 nxB = *(const float2*)(xB + c), nrB = *(const float2*)(rB + c);
    const float  nxnA = xA[cn], nrnA = rA[cn];
    const float  nxnB = xB[cn], nrnB = rB[cn];

    // ---------------- stream A ----------------
    const float dv0A = xcA.x - xcA.y, ev0A = rcA.x - rcA.y;
    float dv1A = xcA.y - xnA,         ev1A = rcA.y - rnA;
    if (tlast){ dv1A = 0.f; ev1A = 0.f; }
    v00 = fmaf(dv0A,ev0A,v00); v01 = fmaf(dv0A,dv0A,v01); v02 = fmaf(ev0A,ev0A,v02);
    v10 = fmaf(dv1A,ev1A,v10); v11 = fmaf(dv1A,dv1A,v11); v12 = fmaf(ev1A,ev1A,v12);
    float pv0A = dv0A*ev0A; pv0A = fmaf(dv1A,ev1A,pv0A);
    float pv1A = dv0A*dv0A; pv1A = fmaf(dv1A,dv1A,pv1A);
    float pv2A = ev0A*ev0A; pv2A = fmaf(ev1A,ev1A,pv2A);
    const float dh0A = xcA.x - nxA.x, eh0A = rcA.x - nrA.x;
    const float dh1A = xcA.y - nxA.y, eh1A = rcA.y - nrA.y;
    h00 = fmaf(dh0A,eh0A,h00); h01 = fmaf(dh0A,dh0A,h01); h02 = fmaf(eh0A,eh0A,h02);
    h10 = fmaf(dh1A,eh1A,h10); h11 = fmaf(dh1A,dh1A,h11); h12 = fmaf(eh1A,eh1A,h12);
    float ph0A = dh0A*eh0A; ph0A = fmaf(dh1A,eh1A,ph0A);
    float ph1A = dh0A*dh0A; ph1A = fmaf(dh1A,dh1A,ph1A);
    float ph2A = eh0A*eh0A; ph2A = fmaf(eh1A,eh1A,ph2A);

    // ---------------- stream B ----------------
    const float dv0B = xcB.x - xcB.y, ev0B = rcB.x - rcB.y;
    float dv1B = xcB.y - xnB,         ev1B = rcB.y - rnB;
    if (tlast){ dv1B = 0.f; ev1B = 0.f; }
    v00 = fmaf(dv0B,ev0B,v00); v01 = fmaf(dv0B,dv0B,v01); v02 = fmaf(ev0B,ev0B,v02);
    v10 = fmaf(dv1B,ev1B,v10); v11 = fmaf(dv1B,dv1B,v11); v12 = fmaf(ev1B,ev1B,v12);
    float pv0B = dv0B*ev0B; pv0B = fmaf(dv1B,ev1B,pv0B);
    float pv1B = dv0B*dv0B; pv1B = fmaf(dv1B,dv1B,pv1B);
    float pv2B = ev0B*ev0B; pv2B = fmaf(ev1B,ev1B,pv2B);
    const float dh0B = xcB.x - nxB.x, eh0B = rcB.x - nrB.x;
    const float dh1B = xcB.y - nxB.y, eh1B = rcB.y - nrB.y;
    h00 = fmaf(dh0B,eh0B,h00); h01 = fmaf(dh0B,dh0B,h01); h02 = fmaf(eh0B,eh0B,h02);
    h10 = fmaf(dh1B,eh1B,h10); h11 = fmaf(dh1B,dh1B,h11); h12 = fmaf(eh1B,eh1B,h12);
    float ph0B = dh0B*eh0B; ph0B = fmaf(dh1B,eh1B,ph0B);
    float ph1B = dh0B*dh0B; ph1B = fmaf(dh1B,dh1B,ph1B);
    float ph2B = eh0B*eh0B; ph2B = fmaf(eh1B,eh1B,ph2B);

    // ---- 12 independent DPP chains (VALU pipe, ILP=12)
    pv0A = wave_dpp_sum(pv0A); pv1A = wave_dpp_sum(pv1A); pv2A = wave_dpp_sum(pv2A);
    ph0A = wave_dpp_sum(ph0A); ph1A = wave_dpp_sum(ph1A); ph2A = wave_dpp_sum(ph2A);
    pv0B = wave_dpp_sum(pv0B); pv1B = wave_dpp_sum(pv1B); pv2B = wave_dpp_sum(pv2B);
    ph0B = wave_dpp_sum(ph0B); ph1B = wave_dpp_sum(ph1B); ph2B = wave_dpp_sum(ph2B);
    if (l == 63){
      rowbuf[k][w][0]=pv0A; rowbuf[k][w][1]=pv1A; rowbuf[k][w][2]=pv2A;
      rowbuf[k][w][3]=ph0A; rowbuf[k][w][4]=ph1A; rowbuf[k][w][5]=ph2A;
      rowbuf[HS+k][w][0]=pv0B; rowbuf[HS+k][w][1]=pv1B; rowbuf[HS+k][w][2]=pv2B;
      rowbuf[HS+k][w][3]=ph0B; rowbuf[HS+k][w][4]=ph1B; rowbuf[HS+k][w][5]=ph2B;
    }

    xcA = nxA; rcA = nrA; xnA = nxnA; rnA = nrnA;
    xcB = nxB; rcB = nrB; xnB = nxnB; rnB = nrnB;
  }

  // ---- col partials: pure per-thread, atomic-free slot store
  float* slot = colPart + (size_t)bid * (6*512);
  *(float2*)(slot + 0*512 + c) = make_float2(v00, v10);
  *(float2*)(slot + 1*512 + c) = make_float2(v01, v11);
  *(float2*)(slot + 2*512 + c) = make_float2(v02, v12);
  *(float2*)(slot + 3*512 + c) = make_float2(h00, h10);
  *(float2*)(slot + 4*512 + c) = make_float2(h01, h11);
  *(float2*)(slot + 5*512 + c) = make_float2(h02, h12);

  // ---- row finalize: combine 4 waves per row, cos, block sum (wave 0 only)
  __syncthreads();
  if (tid < 64){
    float rv = 0.f, rh = 0.f;
    if (tid < RB){
      const int h = h0 + tid;
      float a0=0.f,a1=0.f,a2=0.f,b0=0.f,b1=0.f,b2=0.f;
      #pragma unroll
      for (int q = 0; q < 4; ++q){
        a0 += rowbuf[tid][q][0]; a1 += rowbuf[tid][q][1]; a2 += rowbuf[tid][q][2];
        b0 += rowbuf[tid][q][3]; b1 += rowbuf[tid][q][4]; b2 += rowbuf[tid][q][5];
      }
      rv = cos_sim(a0,a1,a2);
      rh = (h < 511) ? cos_sim(b0,b1,b2) : 0.f;
    }
    rv = wave_dpp_sum(rv);
    rh = wave_dpp_sum(rh);
    if (tid == 63){
      rowPart[2*bid+0] = rv;
      rowPart[2*bid+1] = rh;
    }
  }
}

// ---------------- finish: reduce col partials over NB bands ------------------
template<int NB>
__global__ __launch_bounds__(256) void gp_cols(
    const float* __restrict__ colPart, double* __restrict__ dblk)
{
  const int p = blockIdx.x >> 1;
  const int f = blockIdx.x & 1;    // 0 = fv, 1 = fh
  const int tid = threadIdx.x;
  double acc = 0.0;
  for (int c = tid; c < 512; c += 256){
    float d = 0.f, a = 0.f, b = 0.f;
    #pragma unroll
    for (int s = 0; s < NB; ++s){
      const float* sp = colPart + ((size_t)(p*NB + s) * 6 + f*3) * 512;
      d += sp[c]; a += sp[512 + c]; b += sp[1024 + c];
    }
    acc += (double)cos_sim(d, a, b);   // fv col 511: cos(0,0,0)=0, harmless
  }
  #pragma unroll
  for (int m = 1; m < 64; m <<= 1) acc += __shfl_xor(acc, m, 64);
  __shared__ double ls[4];
  const int w = tid >> 6, l = tid & 63;
  if (l == 0) ls[w] = acc;
  __syncthreads();
  if (tid == 0) dblk[blockIdx.x] = ls[0] + ls[1] + ls[2] + ls[3];
}

__global__ __launch_bounds__(256) void gp_fin(
    const double* __restrict__ dblk, const float* __restrict__ rowPart,
    int nblk, float* __restrict__ out)
{
  const int tid = threadIdx.x;
  double rv = 0, rh = 0, cv = 0, ch = 0;
  for (int i = tid; i < nblk; i += 256){
    rv += (double)rowPart[2*i];
    rh += (double)rowPart[2*i+1];
  }
  for (int i = tid; i < 192; i += 256){
    if (i & 1) ch += dblk[i]; else cv += dblk[i];
  }
  #pragma unroll
  for (int m = 1; m < 64; m <<= 1){
    rv += __shfl_xor(rv, m, 64); rh += __shfl_xor(rh, m, 64);
    cv += __shfl_xor(cv, m, 64); ch += __shfl_xor(ch, m, 64);
  }
  __shared__ double ls[4][4];
  const int w = tid >> 6, l = tid & 63;
  if (l == 0){ ls[w][0]=rv; ls[w][1]=rh; ls[w][2]=cv; ls[w][3]=ch; }
  __syncthreads();
  if (tid == 0){
    double RV=0, RH=0, CV=0, CH=0;
    #pragma unroll
    for (int i = 0; i < 4; ++i){ RV+=ls[i][0]; RH+=ls[i][1]; CV+=ls[i][2]; CH+=ls[i][3]; }
    const double t = RV/512.0 + RH/511.0 + CV/511.0 + CH/512.0;
    out[0] = (float)(-t / 32.0);
  }
}

extern "C" void kernel_launch(void* const* d_in, const int* in_sizes, int n_in,
                              void* d_out, int out_size, void* d_ws, size_t ws_size,
                              hipStream_t stream) {
  const float* X = (const float*)d_in[0];
  const float* R = (const float*)d_in[1];
  float* out = (float*)d_out;

  const size_t need32 = (size_t)96*32*6*512*4 + (size_t)96*32*2*4 + 192*8;
  const size_t need16 = (size_t)96*16*6*512*4 + (size_t)96*16*2*4 + 192*8;

  if (ws_size >= need32){
    constexpr int NB = 32;                                 // 16-row bands
    float*  colPart = (float*)d_ws;
    float*  rowPart = colPart + (size_t)96*NB*6*512;
    double* dblk    = (double*)(rowPart + (size_t)96*NB*2);
    gp_uni<16><<<dim3(96*NB), dim3(256), 0, stream>>>(X, R, rowPart, colPart);
    gp_cols<NB><<<dim3(192),  dim3(256), 0, stream>>>(colPart, dblk);
    gp_fin     <<<dim3(1),    dim3(256), 0, stream>>>(dblk, rowPart, 96*NB, out);
  } else if (ws_size >= need16){
    constexpr int NB = 16;                                 // 32-row bands
    float*  colPart = (float*)d_ws;
    float*  rowPart = colPart + (size_t)96*NB*6*512;
    double* dblk    = (double*)(rowPart + (size_t)96*NB*2);
    gp_uni<32><<<dim3(96*NB), dim3(256), 0, stream>>>(X, R, rowPart, colPart);
    gp_cols<NB><<<dim3(192),  dim3(256), 0, stream>>>(colPart, dblk);
    gp_fin     <<<dim3(1),    dim3(256), 0, stream>>>(dblk, rowPart, 96*NB, out);
  } else {
    constexpr int NB = 8;                                  // 64-row bands
    float*  colPart = (float*)d_ws;
    float*  rowPart = colPart + (size_t)96*NB*6*512;
    double* dblk    = (double*)(rowPart + (size_t)96*NB*2);
    gp_uni<64><<<dim3(96*NB), dim3(256), 0, stream>>>(X, R, rowPart, colPart);
    gp_cols<NB><<<dim3(192),  dim3(256), 0, stream>>>(colPart, dblk);
    gp_fin     <<<dim3(1),    dim3(256), 0, stream>>>(dblk, rowPart, 96*NB, out);
  }
}

// Round 8
// 51.871 us; speedup vs baseline: 1.9143x; 1.9143x over previous
//
#include <hip/hip_runtime.h>

// GPLoss: gradient-profile loss, scalar output.
// Main pass: thread owns 4 cols (float4); block = 4 waves on a 32-row band
// pair (waves 0-1: rows [0,16), waves 2-3: rows [16,32); each wave = 256 cols).
// Row stats: 6 DPP chains/wave/row -> rowbuf LDS; col stats: per-thread regs
// -> LDS band-merge -> one colPart slot per block (96*16 slots = 18.9 MB,
// kept small so inputs stay L3-resident across timed replays).
// ws: colPart f32[96*16][6][512] ; rowPart f32[1536][2] ; dblk f64[192]

#define DPP_ADD(x, ctrl, rmask) \
  x += __int_as_float(__builtin_amdgcn_update_dpp(0, __float_as_int(x), ctrl, rmask, 0xf, false))

__device__ __forceinline__ float wave_dpp_sum(float x){
  DPP_ADD(x, 0x111, 0xf);   // row_shr:1
  DPP_ADD(x, 0x112, 0xf);   // row_shr:2
  DPP_ADD(x, 0x114, 0xf);   // row_shr:4
  DPP_ADD(x, 0x118, 0xf);   // row_shr:8
  DPP_ADD(x, 0x142, 0xa);   // row_bcast:15 -> rows 1,3
  DPP_ADD(x, 0x143, 0xc);   // row_bcast:31 -> rows 2,3
  return x;                 // lane 63 holds the 64-lane sum
}

__device__ __forceinline__ float cos_sim(float d, float sx, float sr){
  float nx = fmaxf(sqrtf(sx), 1e-12f);
  float nr = fmaxf(sqrtf(sr), 1e-12f);
  return d / (nx * nr);
}

__global__ __launch_bounds__(256) void gp_uni(
    const float* __restrict__ X, const float* __restrict__ R,
    float* __restrict__ rowPart, float* __restrict__ colPart)
{
  const int bid = blockIdx.x;
  const int p = bid >> 4, q = bid & 15;        // plane, band-pair (32 rows)
  const int tid = threadIdx.x, w = tid >> 6, l = tid & 63;
  const int half = w >> 1;                      // 0: rows [0,16)  1: [16,32)
  const int wp   = w & 1;                       // col half: wp*256
  const size_t plane = (size_t)p * (512u*512u);
  const float* xp = X + plane;
  const float* rp = R + plane;
  const int c  = wp*256 + 4*l;                  // cols c..c+3
  const int cn = (c+4 < 512) ? c+4 : 511;       // f_v halo col (clamped)
  const bool tlast = (c == 508);                // col 511: no f_v
  const int h0 = q*32 + half*16;                // first row of this wave-pair

  __shared__ float colbuf[6][512];              // 12 KB band-merge
  __shared__ float rowbuf[32][2][6];            // 1.5 KB row stats

  float cv0[4], cv1[4], cv2[4], ch0[4], ch1[4], ch2[4];
  #pragma unroll
  for (int j = 0; j < 4; ++j){
    cv0[j]=0.f; cv1[j]=0.f; cv2[j]=0.f;
    ch0[j]=0.f; ch1[j]=0.f; ch2[j]=0.f;
  }

  const float* xr0 = xp + (size_t)h0*512;
  const float* rr0 = rp + (size_t)h0*512;
  float4 xc4 = *(const float4*)(xr0 + c);
  float4 rc4 = *(const float4*)(rr0 + c);
  float  xhv = xr0[cn], rhv = rr0[cn];

  #pragma unroll 2
  for (int k = 0; k < 16; ++k){
    const int h  = h0 + k;
    const int hn = (h+1 < 512) ? h+1 : 511;     // h==511: next==cur -> dh=0
    const float* xr = xp + (size_t)hn*512;
    const float* rr = rp + (size_t)hn*512;
    const float4 nx4 = *(const float4*)(xr + c);
    const float4 nr4 = *(const float4*)(rr + c);
    const float  nxh = xr[cn], nrh = rr[cn];

    const float ax[4] = {xc4.x, xc4.y, xc4.z, xc4.w};
    const float ar[4] = {rc4.x, rc4.y, rc4.z, rc4.w};
    const float bx[4] = {nx4.x, nx4.y, nx4.z, nx4.w};
    const float br[4] = {nr4.x, nr4.y, nr4.z, nr4.w};

    float dv[4], ev[4];
    dv[0]=ax[0]-ax[1]; dv[1]=ax[1]-ax[2]; dv[2]=ax[2]-ax[3];
    ev[0]=ar[0]-ar[1]; ev[1]=ar[1]-ar[2]; ev[2]=ar[2]-ar[3];
    dv[3] = tlast ? 0.f : (ax[3]-xhv);
    ev[3] = tlast ? 0.f : (ar[3]-rhv);

    float p0=0.f,p1=0.f,p2=0.f, q0=0.f,q1=0.f,q2=0.f;
    #pragma unroll
    for (int j = 0; j < 4; ++j){
      p0 = fmaf(dv[j],ev[j],p0); p1 = fmaf(dv[j],dv[j],p1); p2 = fmaf(ev[j],ev[j],p2);
      cv0[j] = fmaf(dv[j],ev[j],cv0[j]);
      cv1[j] = fmaf(dv[j],dv[j],cv1[j]);
      cv2[j] = fmaf(ev[j],ev[j],cv2[j]);
      const float dh = ax[j]-bx[j];
      const float eh = ar[j]-br[j];
      q0 = fmaf(dh,eh,q0); q1 = fmaf(dh,dh,q1); q2 = fmaf(eh,eh,q2);
      ch0[j] = fmaf(dh,eh,ch0[j]);
      ch1[j] = fmaf(dh,dh,ch1[j]);
      ch2[j] = fmaf(eh,eh,ch2[j]);
    }

    // 6 independent DPP chains (VALU pipe)
    p0 = wave_dpp_sum(p0); p1 = wave_dpp_sum(p1); p2 = wave_dpp_sum(p2);
    q0 = wave_dpp_sum(q0); q1 = wave_dpp_sum(q1); q2 = wave_dpp_sum(q2);
    if (l == 63){
      const int rr_ = half*16 + k;
      rowbuf[rr_][wp][0]=p0; rowbuf[rr_][wp][1]=p1; rowbuf[rr_][wp][2]=p2;
      rowbuf[rr_][wp][3]=q0; rowbuf[rr_][wp][4]=q1; rowbuf[rr_][wp][5]=q2;
    }

    xc4 = nx4; rc4 = nr4; xhv = nxh; rhv = nrh;
  }

  // ---- col stats: band A writes, band B accumulates, then stream out
  if (half == 0){
    *(float4*)&colbuf[0][c] = make_float4(cv0[0],cv0[1],cv0[2],cv0[3]);
    *(float4*)&colbuf[1][c] = make_float4(cv1[0],cv1[1],cv1[2],cv1[3]);
    *(float4*)&colbuf[2][c] = make_float4(cv2[0],cv2[1],cv2[2],cv2[3]);
    *(float4*)&colbuf[3][c] = make_float4(ch0[0],ch0[1],ch0[2],ch0[3]);
    *(float4*)&colbuf[4][c] = make_float4(ch1[0],ch1[1],ch1[2],ch1[3]);
    *(float4*)&colbuf[5][c] = make_float4(ch2[0],ch2[1],ch2[2],ch2[3]);
  }
  __syncthreads();
  if (half == 1){
    float4 t;
    t = *(float4*)&colbuf[0][c]; t.x+=cv0[0]; t.y+=cv0[1]; t.z+=cv0[2]; t.w+=cv0[3]; *(float4*)&colbuf[0][c]=t;
    t = *(float4*)&colbuf[1][c]; t.x+=cv1[0]; t.y+=cv1[1]; t.z+=cv1[2]; t.w+=cv1[3]; *(float4*)&colbuf[1][c]=t;
    t = *(float4*)&colbuf[2][c]; t.x+=cv2[0]; t.y+=cv2[1]; t.z+=cv2[2]; t.w+=cv2[3]; *(float4*)&colbuf[2][c]=t;
    t = *(float4*)&colbuf[3][c]; t.x+=ch0[0]; t.y+=ch0[1]; t.z+=ch0[2]; t.w+=ch0[3]; *(float4*)&colbuf[3][c]=t;
    t = *(float4*)&colbuf[4][c]; t.x+=ch1[0]; t.y+=ch1[1]; t.z+=ch1[2]; t.w+=ch1[3]; *(float4*)&colbuf[4][c]=t;
    t = *(float4*)&colbuf[5][c]; t.x+=ch2[0]; t.y+=ch2[1]; t.z+=ch2[2]; t.w+=ch2[3]; *(float4*)&colbuf[5][c]=t;
  }
  __syncthreads();
  float4* slot = (float4*)(colPart + (size_t)bid * (6*512));
  const float4* cb = (const float4*)colbuf;
  #pragma unroll
  for (int i = 0; i < 3; ++i) slot[tid + 256*i] = cb[tid + 256*i];

  // ---- row finalize: combine col-half pairs, cos, block sum (wave 0)
  if (tid < 64){
    float rv = 0.f, rh = 0.f;
    if (tid < 32){
      const float a0 = rowbuf[tid][0][0] + rowbuf[tid][1][0];
      const float a1 = rowbuf[tid][0][1] + rowbuf[tid][1][1];
      const float a2 = rowbuf[tid][0][2] + rowbuf[tid][1][2];
      const float b0 = rowbuf[tid][0][3] + rowbuf[tid][1][3];
      const float b1 = rowbuf[tid][0][4] + rowbuf[tid][1][4];
      const float b2 = rowbuf[tid][0][5] + rowbuf[tid][1][5];
      rv = cos_sim(a0,a1,a2);
      const int h = q*32 + tid;
      rh = (h < 511) ? cos_sim(b0,b1,b2) : 0.f;
    }
    rv = wave_dpp_sum(rv);
    rh = wave_dpp_sum(rh);
    if (tid == 63){
      rowPart[2*bid+0] = rv;
      rowPart[2*bid+1] = rh;
    }
  }
}

// ---------------- finish: reduce col partials over 16 slots ------------------
__global__ __launch_bounds__(256) void gp_cols(
    const float* __restrict__ colPart, double* __restrict__ dblk)
{
  const int p = blockIdx.x >> 1;
  const int f = blockIdx.x & 1;    // 0 = fv, 1 = fh
  const int tid = threadIdx.x;
  double acc = 0.0;
  for (int c = tid; c < 512; c += 256){
    float d = 0.f, a = 0.f, b = 0.f;
    #pragma unroll
    for (int s = 0; s < 16; ++s){
      const float* sp = colPart + ((size_t)(p*16 + s) * 6 + f*3) * 512;
      d += sp[c]; a += sp[512 + c]; b += sp[1024 + c];
    }
    acc += (double)cos_sim(d, a, b);   // fv col 511: cos(0,0,0)=0, harmless
  }
  #pragma unroll
  for (int m = 1; m < 64; m <<= 1) acc += __shfl_xor(acc, m, 64);
  __shared__ double ls[4];
  const int w = tid >> 6, l = tid & 63;
  if (l == 0) ls[w] = acc;
  __syncthreads();
  if (tid == 0) dblk[blockIdx.x] = ls[0] + ls[1] + ls[2] + ls[3];
}

__global__ __launch_bounds__(256) void gp_fin(
    const double* __restrict__ dblk, const float* __restrict__ rowPart,
    int nblk, float* __restrict__ out)
{
  const int tid = threadIdx.x;
  double rv = 0, rh = 0, cv = 0, ch = 0;
  for (int i = tid; i < nblk; i += 256){
    rv += (double)rowPart[2*i];
    rh += (double)rowPart[2*i+1];
  }
  for (int i = tid; i < 192; i += 256){
    if (i & 1) ch += dblk[i]; else cv += dblk[i];
  }
  #pragma unroll
  for (int m = 1; m < 64; m <<= 1){
    rv += __shfl_xor(rv, m, 64); rh += __shfl_xor(rh, m, 64);
    cv += __shfl_xor(cv, m, 64); ch += __shfl_xor(ch, m, 64);
  }
  __shared__ double ls[4][4];
  const int w = tid >> 6, l = tid & 63;
  if (l == 0){ ls[w][0]=rv; ls[w][1]=rh; ls[w][2]=cv; ls[w][3]=ch; }
  __syncthreads();
  if (tid == 0){
    double RV=0, RH=0, CV=0, CH=0;
    #pragma unroll
    for (int i = 0; i < 4; ++i){ RV+=ls[i][0]; RH+=ls[i][1]; CV+=ls[i][2]; CH+=ls[i][3]; }
    const double t = RV/512.0 + RH/511.0 + CV/511.0 + CH/512.0;
    out[0] = (float)(-t / 32.0);
  }
}

extern "C" void kernel_launch(void* const* d_in, const int* in_sizes, int n_in,
                              void* d_out, int out_size, void* d_ws, size_t ws_size,
                              hipStream_t stream) {
  const float* X = (const float*)d_in[0];
  const float* R = (const float*)d_in[1];
  float* out = (float*)d_out;

  float*  colPart = (float*)d_ws;                         // 96*16*6*512 f32
  float*  rowPart = colPart + (size_t)96*16*6*512;        // 1536*2 f32
  double* dblk    = (double*)(rowPart + (size_t)1536*2);  // 192 f64

  gp_uni <<<dim3(1536), dim3(256), 0, stream>>>(X, R, rowPart, colPart);
  gp_cols<<<dim3(192),  dim3(256), 0, stream>>>(colPart, dblk);
  gp_fin <<<dim3(1),    dim3(256), 0, stream>>>(dblk, rowPart, 1536, out);
}